// Round 2
// baseline (245.487 us; speedup 1.0000x reference)
//
#include <hip/hip_runtime.h>

#define HBITS 19u
#define HSIZE (1u << HBITS)
#define HMASK (HSIZE - 1u)
#define ECAP  (1 << 20)           // extras capacity (pairs); test input needs ~9K
#define EMPTY64 0xFFFFFFFFFFFFFFFFull

constexpr int CD = 41, CH = 1024, CW = 1024;

// ---------------- setup: clear hash table, flags, counters ----------------

__global__ __launch_bounds__(256) void setup(unsigned long long* __restrict__ tab,
                                             int* __restrict__ flags, int n,
                                             int* __restrict__ cnt, int* __restrict__ scnt) {
    unsigned i = blockIdx.x * blockDim.x + threadIdx.x;
    if (i < HSIZE) tab[i] = EMPTY64;
    if (i < (unsigned)n) flags[i] = 0;
    if (i == 0) { *cnt = 0; *scnt = 0; }
}

// ---------------- hash table: 64-bit records (idx<<32 | lin), linear probe ----------------

__global__ __launch_bounds__(256) void hash_insert(const int* __restrict__ coors, int n,
                                                   unsigned long long* __restrict__ tab) {
    int i = blockIdx.x * blockDim.x + threadIdx.x;
    if (i >= n) return;
    int b = coors[4 * i], z = coors[4 * i + 1], y = coors[4 * i + 2], x = coors[4 * i + 3];
    unsigned lin = (((unsigned)b * CD + (unsigned)z) * CH + (unsigned)y) * CW + (unsigned)x;
    unsigned h = (lin * 2654435761u) >> (32u - HBITS);
    unsigned long long rec = ((unsigned long long)(unsigned)i << 32) | (unsigned long long)lin;
    while (true) {
        unsigned long long prev = atomicCAS(&tab[h], EMPTY64, rec);
        if (prev == EMPTY64) break;
        h = (h + 1u) & HMASK;
    }
}

__device__ __forceinline__ int hash_lookup(unsigned lin, const unsigned long long* __restrict__ tab) {
    unsigned h = (lin * 2654435761u) >> (32u - HBITS);
    while (true) {
        unsigned long long v = tab[h];
        if ((unsigned)v == lin) return (int)(v >> 32);
        if (v == EMPTY64) return -1;
        h = (h + 1u) & HMASK;
    }
}

// ---------------- compact extras + mark S membership ----------------
// mirror symmetry: (i,k,j) valid <=> (j,26-k,i) valid -> scan k<13, emit both, flag both.

__global__ __launch_bounds__(256) void build_extras(const int* __restrict__ coors, int n,
                                                    const unsigned long long* __restrict__ tab,
                                                    int2* __restrict__ extras,
                                                    int* __restrict__ cnt,
                                                    int* __restrict__ flags) {
    int i = blockIdx.x * blockDim.x + threadIdx.x;
    if (i >= n) return;
    int b = coors[4 * i], z = coors[4 * i + 1], y = coors[4 * i + 2], x = coors[4 * i + 3];
    for (int k = 0; k < 13; ++k) {
        int dz = k / 9 - 1, dy = (k / 3) % 3 - 1, dx = k % 3 - 1;
        int nz = z + dz, ny = y + dy, nx = x + dx;
        if (nz < 0 || nz >= CD || ny < 0 || ny >= CH || nx < 0 || nx >= CW) continue;
        unsigned lin = (((unsigned)b * CD + (unsigned)nz) * CH + (unsigned)ny) * CW + (unsigned)nx;
        int j = hash_lookup(lin, tab);
        if (j >= 0) {
            int pos = atomicAdd(cnt, 2);          // even; ECAP even -> no straddle
            if (pos + 1 < ECAP) {
                extras[pos]     = make_int2((i << 5) | k,        j);
                extras[pos + 1] = make_int2((j << 5) | (26 - k), i);
                flags[i] = 1;
                flags[j] = 1;
            }
        }
    }
}

__global__ __launch_bounds__(256) void compact_S(const int* __restrict__ flags, int n,
                                                 int* __restrict__ Slist, int* __restrict__ scnt) {
    int i = blockIdx.x * blockDim.x + threadIdx.x;
    if (i < n && flags[i]) { int s = atomicAdd(scnt, 1); Slist[s] = i; }
}

// ---------------- weight prep: PT = (W0c@W1c@W2c)^T, WT[l] = Wlc^T ----------------

__global__ __launch_bounds__(256) void make_weights(const float* __restrict__ Ws,
                                                    float* __restrict__ PT,
                                                    float* __restrict__ WT) {
    __shared__ float T[64][64];
    int tid = threadIdx.x;
    const float* W0 = Ws + (0 * 27 + 13) * 4096;
    const float* W1 = Ws + (1 * 27 + 13) * 4096;
    const float* W2 = Ws + (2 * 27 + 13) * 4096;
    for (int l = 0; l < 3; ++l) {
        const float* W = Ws + (l * 27 + 13) * 4096;
        for (int e = tid; e < 4096; e += 256) {
            int o = e >> 6, c = e & 63;
            WT[l * 4096 + e] = W[c * 64 + o];          // WT[l][o][c] = W[c][o]
        }
    }
    for (int e = tid; e < 4096; e += 256) {            // T = W0c @ W1c
        int r = e >> 6, c2 = e & 63;
        float s = 0.f;
        for (int c1 = 0; c1 < 64; ++c1) s = fmaf(W0[r * 64 + c1], W1[c1 * 64 + c2], s);
        T[r][c2] = s;
    }
    __syncthreads();
    for (int e = tid; e < 4096; e += 256) {            // PT = (T @ W2c)^T
        int r = e >> 6, c2 = e & 63;
        float s = 0.f;
        for (int c1 = 0; c1 < 64; ++c1) s = fmaf(T[r][c1], W2[c1 * 64 + c2], s);
        PT[c2 * 64 + r] = s;
    }
}

// ---------------- row GEMM: out[p] = x[p] @ W  (W passed transposed: WT[o][c]) ----
// Wave iterates points; lane = out channel; W column resident in 64 VGPRs;
// x row via wave-uniform pointer -> scalar loads; one coalesced 256B store/point.

__global__ __launch_bounds__(256) void row_gemm(const float* __restrict__ xin,
                                                float* __restrict__ xout,
                                                const float* __restrict__ WTm,  // [64][64] transposed
                                                const int* __restrict__ list,   // nullptr -> identity
                                                const int* __restrict__ listCnt,// nullptr -> n
                                                int n) {
    int wv = (int)((blockIdx.x * blockDim.x + threadIdx.x) >> 6);
    int nwv = (int)((gridDim.x * blockDim.x) >> 6);
    int lane = threadIdx.x & 63;
    int cnt = listCnt ? *listCnt : n;

    float w[64];
    const float4* wt4 = (const float4*)(WTm + lane * 64);
#pragma unroll
    for (int t = 0; t < 16; ++t) ((float4*)w)[t] = wt4[t];

    for (int it = wv; it < cnt; it += nwv) {
        int p = list ? list[it] : it;
        p = __builtin_amdgcn_readfirstlane(p);
        const float* xr = xin + (size_t)p * 64;
        float acc = 0.f;
#pragma unroll
        for (int c = 0; c < 64; ++c) acc = fmaf(xr[c], w[c], acc);
        xout[(size_t)p * 64 + lane] = acc;
    }
}

// ---------------- sparse residual: out[i] += x[j] @ W[k] per extra pair ----------------

__global__ __launch_bounds__(256) void residual(const float* __restrict__ xin,
                                                float* __restrict__ xout,
                                                const float* __restrict__ Wl,   // [27][64][64]
                                                const int2* __restrict__ extras,
                                                const int* __restrict__ cnt) {
    int m = *cnt; if (m > ECAP) m = ECAP;
    int nw = (int)((gridDim.x * blockDim.x) >> 6);
    int gw = (int)((blockIdx.x * blockDim.x + threadIdx.x) >> 6);
    int lane = threadIdx.x & 63;
    for (int e = gw; e < m; e += nw) {
        int2 pr = extras[e];
        int i = pr.x >> 5, k = pr.x & 31, j = pr.y;
        float xj = xin[(size_t)j * 64 + lane];
        const float* Wk = Wl + k * 4096;
        float acc = 0.f;
#pragma unroll
        for (int c = 0; c < 64; ++c)
            acc = fmaf(__shfl(xj, c), Wk[c * 64 + lane], acc);
        atomicAdd(&xout[(size_t)i * 64 + lane], acc);
    }
}

// ---------------- launch ----------------

extern "C" void kernel_launch(void* const* d_in, const int* in_sizes, int n_in,
                              void* d_out, int out_size, void* d_ws, size_t ws_size,
                              hipStream_t stream) {
    const float* features = (const float*)d_in[0];
    const float* Ws       = (const float*)d_in[1];   // [3][27][64][64]
    const int*   coors    = (const int*)d_in[2];
    int n = in_sizes[0] / 64;

    // workspace layout (256B-aligned chunks)
    char* p = (char*)d_ws;
    unsigned long long* tab = (unsigned long long*)p; p += (size_t)HSIZE * 8;
    int* cnt  = (int*)p;
    int* scnt = cnt + 1;                              p += 256;
    int2* extras = (int2*)p;                          p += (size_t)ECAP * 8;
    int* flags = (int*)p;                             p += (((size_t)n * 4 + 255) & ~255ull);
    int* Slist = (int*)p;                             p += (((size_t)n * 4 + 255) & ~255ull);
    float* bufA = (float*)p;                          p += (((size_t)n * 256 + 255) & ~255ull);
    float* bufB = (float*)p;                          p += (((size_t)n * 256 + 255) & ~255ull);
    float* PT = (float*)p;                            p += 16384;
    float* WT = (float*)p;                            p += 3 * 16384;
    float* out = (float*)d_out;

    const float* W0 = Ws + 0 * 27 * 4096;
    const float* W1 = Ws + 1 * 27 * 4096;
    const float* W2 = Ws + 2 * 27 * 4096;

    setup<<<(HSIZE + 255) / 256, 256, 0, stream>>>(tab, flags, n, cnt, scnt);
    hash_insert<<<(n + 255) / 256, 256, 0, stream>>>(coors, n, tab);
    make_weights<<<1, 256, 0, stream>>>(Ws, PT, WT);
    build_extras<<<(n + 255) / 256, 256, 0, stream>>>(coors, n, tab, extras, cnt, flags);
    compact_S<<<(n + 255) / 256, 256, 0, stream>>>(flags, n, Slist, scnt);

    // dense collapsed 3-layer pass for all points: out = features @ (W0c W1c W2c)
    row_gemm<<<1024, 256, 0, stream>>>(features, out, PT, nullptr, nullptr, n);

    // sparse S-pass: true per-layer propagation for points with neighbors (closed set)
    // layer 0: features -> bufA (S rows only)
    row_gemm<<<128, 256, 0, stream>>>(features, bufA, WT + 0 * 4096, Slist, scnt, n);
    residual<<<128, 256, 0, stream>>>(features, bufA, W0, extras, cnt);
    // layer 1: bufA -> bufB
    row_gemm<<<128, 256, 0, stream>>>(bufA, bufB, WT + 1 * 4096, Slist, scnt, n);
    residual<<<128, 256, 0, stream>>>(bufA, bufB, W1, extras, cnt);
    // layer 2: bufB -> out (overwrites dense result on S rows; dense ran first)
    row_gemm<<<128, 256, 0, stream>>>(bufB, out, WT + 2 * 4096, Slist, scnt, n);
    residual<<<128, 256, 0, stream>>>(bufB, out, W2, extras, cnt);
}